// Round 1
// 186.448 us; speedup vs baseline: 1.0255x; 1.0255x over previous
//
#include <hip/hip_runtime.h>

// AlgebraicAttention on MI355X (gfx950), round 11.
// R10 post-mortem: gemm_qkv 49us = 527 TF, MfmaUtil 19.6%, HBM 20% -> classic
// 2-phase stage+barrier stall (m233 regime). Fix: port gemm_qkv to the 256x256
// 8-phase template (T2 swizzle + T3/T4 counted-vmcnt phases + T5 setprio), which
// is the only quadrant where those techniques pay (m201/m230 regime gate).
// Schedule: LDS [2buf][2 khalf][256x32] per operand (128 KiB); 4 phases/K-tile =
// (khalf x C-half), each {ds_read 4-8 x b128, issue 1 half-tile prefetch, barrier,
// setprio(1), 16 MFMA, setprio(0), barrier}; during tile T stage T+1.k1 (ph1/2)
// and T+2.k0 (ph3/4, into buf T&1 after its k0 reads finished); ONE vmcnt(4) gate
// per tile, vmcnt(0) only in the last tile. 192 blocks x 512thr (Q 16x4, K 16x4,
// V^T 4x16), XCD-chunked remap (192%8==0 bijective). cast/attn/gemm_out unchanged.
// ws: [0,8M) xb | [8,10M) wqb | [10,12M) wkb | [12,14M) wvb | [14,16M) wob |
//     [16,24M) Qb (att in-place). d_out: [0,8M) Kb | [8,16M) Vtg (V^T).

typedef __attribute__((ext_vector_type(8))) __bf16 bf16x8;
typedef __attribute__((ext_vector_type(4))) __bf16 bf16x4;
typedef __attribute__((ext_vector_type(4))) float f32x4;
typedef unsigned short u16;

__device__ __forceinline__ u16 f2bf(float f) {
  unsigned u = __float_as_uint(f);
  u += 0x7FFFu + ((u >> 16) & 1u);   // round-to-nearest-even
  return (u16)(u >> 16);
}
__device__ __forceinline__ float bf2f(u16 b) {
  return __uint_as_float(((unsigned)b) << 16);
}
__device__ __forceinline__ void gl_lds16(const void* g, void* l) {
  __builtin_amdgcn_global_load_lds((__attribute__((address_space(1))) void*)g,
                                   (__attribute__((address_space(3))) void*)l,
                                   16, 0, 0);
}

// ---------------------------------------------------------------- cast kernel
__global__ __launch_bounds__(256) void cast_all_kernel(
    const float* __restrict__ x,  const float* __restrict__ wq,
    const float* __restrict__ wk, const float* __restrict__ wv,
    const float* __restrict__ wo,
    u16* __restrict__ xb, u16* __restrict__ wqb, u16* __restrict__ wkb,
    u16* __restrict__ wvb, u16* __restrict__ wob) {
  long i4 = (long)blockIdx.x * 256 + threadIdx.x;
  const float* src; u16* dst; long rel;
  if (i4 < 1048576) { src = x; dst = xb; rel = i4; }
  else {
    long j = i4 - 1048576;
    int w = (int)(j >> 18);
    rel = j & 262143;
    src = (w == 0) ? wq : (w == 1) ? wk : (w == 2) ? wv : wo;
    dst = (w == 0) ? wqb : (w == 1) ? wkb : (w == 2) ? wvb : wob;
  }
  float4 v = ((const float4*)src)[rel];
  ushort4 o;
  o.x = f2bf(v.x); o.y = f2bf(v.y); o.z = f2bf(v.z); o.w = f2bf(v.w);
  ((ushort4*)dst)[rel] = o;
}

// ---------------------------------------------------------------- GEMM body (r9, proven)
// C = A @ B^T (+bias). 128x128 tile, BK=64, double-buffered swizzled LDS,
// raw s_barrier + vmcnt(8) pipeline. Kept for gemm_out (256 full-fill blocks).
template <bool STORE_BF16>
__device__ __forceinline__ void gemm_body(
    const u16* __restrict__ A, const u16* __restrict__ B,
    const float* __restrict__ bias, bool rowbias,
    void* __restrict__ Cout, int ldc, int m0, int n0) {
  constexpr int K = 1024;
  constexpr int NT = K / 64;
  __shared__ __align__(16) u16 As[2][128 * 64];
  __shared__ __align__(16) u16 Bs[2][128 * 64];

  const int t = threadIdx.x;
  const int lane = t & 63;
  const int wv = t >> 6;
  const int quad = lane >> 4;
  const int l15 = lane & 15;
  const int wr = wv >> 1, wc = wv & 1;
  const int sw0 = (quad ^ (l15 & 7)) * 8;
  const int sw1 = ((4 + quad) ^ (l15 & 7)) * 8;

  const f32x4 vzero = {0.f, 0.f, 0.f, 0.f};
  f32x4 acc[4][4];
#pragma unroll
  for (int i = 0; i < 4; ++i)
#pragma unroll
    for (int j = 0; j < 4; ++j) acc[i][j] = vzero;

  auto stage = [&](int kt, int bufi) {
#pragma unroll
    for (int p = 0; p < 4; ++p) {
      int idx = t + p * 256;
      int row = idx >> 3, seg = idx & 7;
      int sseg = seg ^ (row & 7);
      gl_lds16(&A[(long)(m0 + row) * K + kt * 64 + sseg * 8], &As[bufi][idx * 8]);
      gl_lds16(&B[(long)(n0 + row) * K + kt * 64 + sseg * 8], &Bs[bufi][idx * 8]);
    }
  };

  stage(0, 0);
  for (int kt = 0; kt < NT; ++kt) {
    const int bufi = kt & 1;
    if (kt + 1 < NT) {
      stage(kt + 1, bufi ^ 1);
      asm volatile("s_waitcnt vmcnt(8)" ::: "memory");
    } else {
      asm volatile("s_waitcnt vmcnt(0)" ::: "memory");
    }
    asm volatile("s_barrier" ::: "memory");
#pragma unroll
    for (int ks = 0; ks < 64; ks += 32) {
      const int sw = ks ? sw1 : sw0;
      bf16x8 af[4], bfg[4];
#pragma unroll
      for (int i = 0; i < 4; ++i)
        af[i] = *(const bf16x8*)&As[bufi][(wr * 64 + i * 16 + l15) * 64 + sw];
#pragma unroll
      for (int j = 0; j < 4; ++j)
        bfg[j] = *(const bf16x8*)&Bs[bufi][(wc * 64 + j * 16 + l15) * 64 + sw];
#pragma unroll
      for (int i = 0; i < 4; ++i)
#pragma unroll
        for (int j = 0; j < 4; ++j)
          acc[i][j] = __builtin_amdgcn_mfma_f32_16x16x32_bf16(af[i], bfg[j], acc[i][j], 0, 0, 0);
    }
    asm volatile("s_barrier" ::: "memory");
  }

  float cb[4];
  if (!rowbias) {
#pragma unroll
    for (int j = 0; j < 4; ++j) cb[j] = bias[n0 + wc * 64 + j * 16 + l15];
  }

#pragma unroll
  for (int i = 0; i < 4; ++i) {
#pragma unroll
    for (int r = 0; r < 4; ++r) {
      int row = m0 + wr * 64 + i * 16 + quad * 4 + r;
      long base = (long)row * ldc + n0 + wc * 64;
      float rb_ = rowbias ? bias[row] : 0.f;
#pragma unroll
      for (int j = 0; j < 4; ++j) {
        float v = acc[i][j][r] + (rowbias ? rb_ : cb[j]);
        if (STORE_BF16) ((u16*)Cout)[base + j * 16 + l15] = f2bf(v);
        else            ((float*)Cout)[base + j * 16 + l15] = v;
      }
    }
  }
}

// ---------------------------------------------------------------- 256x256 8-phase body
// C = A @ B^T (+bias). BK=64 split into two K-halves of 32. 8 waves (2M x 4N),
// per-wave C = 128x64 (acc[8][4]). LDS: [buf][khalf][256 rows][32 cols] per operand.
// Granule swizzle gs = g ^ ((row>>1)&3): pre-swizzled global source, linear LDS
// dest (global_load_lds requirement), swizzled ds_read -> 2-way max (free).
template <bool STORE_BF16>
__device__ __forceinline__ void gemm256_body(
    const u16* __restrict__ A, const u16* __restrict__ B,
    const float* __restrict__ bias, bool rowbias,
    void* __restrict__ Cout, int ldc, int m0, int n0) {
  constexpr int K = 1024;
  constexpr int NT = K / 64;      // 16 K-tiles
  __shared__ __align__(16) u16 As[2][2][256 * 32];  // 64 KiB
  __shared__ __align__(16) u16 Bs[2][2][256 * 32];  // 64 KiB

  const int t = threadIdx.x;      // 0..511
  const int lane = t & 63;
  const int wv = t >> 6;          // 0..7
  const int wr = wv >> 2;         // 0..1  (M-half of C)
  const int wc = wv & 3;          // 0..3  (N quarter)
  const int quad = lane >> 4;
  const int l15 = lane & 15;

  // per-lane swizzled read bases (u16 elements). (row>>1)&3 is invariant under
  // +16/+64 row steps, so per-(qm,i) offsets are compile-time immediates.
  const int rA = wr * 128 + l15;
  const int rB = wc * 64 + l15;
  const int baseA = rA * 32 + ((quad ^ ((rA >> 1) & 3)) * 8);
  const int baseB = rB * 32 + ((quad ^ ((rB >> 1) & 3)) * 8);

  // per-thread stage source base: row = t>>2 (+128 for 2nd load), granule = t&3,
  // swizzled source granule gs (involution; same for both loads since 128 is even*2)
  const int srow = t >> 2;
  const int sg = (t & 3) ^ ((t >> 3) & 3);
  const long sA = (long)(m0 + srow) * K + sg * 8;
  const long sB = (long)(n0 + srow) * K + sg * 8;

  auto stA = [&](int T_, int kh, int bf_) {
    const u16* s = A + sA + T_ * 64 + kh * 32;
    u16* d = &As[bf_][kh][t * 8];
    gl_lds16(s, d);
    gl_lds16(s + (long)128 * K, d + 4096);
  };
  auto stB = [&](int T_, int kh, int bf_) {
    const u16* s = B + sB + T_ * 64 + kh * 32;
    u16* d = &Bs[bf_][kh][t * 8];
    gl_lds16(s, d);
    gl_lds16(s + (long)128 * K, d + 4096);
  };

  const f32x4 vzero = {0.f, 0.f, 0.f, 0.f};
  f32x4 acc[8][4];
#pragma unroll
  for (int i = 0; i < 8; ++i)
#pragma unroll
    for (int j = 0; j < 4; ++j) acc[i][j] = vzero;

  // prologue: tile0 complete + tile1.k0 in flight; gate leaves newest 4 loads.
  stA(0, 0, 0); stB(0, 0, 0);
  stA(0, 1, 0); stB(0, 1, 0);
  stA(1, 0, 1); stB(1, 0, 1);
  asm volatile("s_waitcnt vmcnt(4)" ::: "memory");
  asm volatile("s_barrier" ::: "memory");

  for (int T = 0; T < NT; ++T) {
    const int c = T & 1;
    const u16* Ac = &As[c][0][0];
    const u16* Bc = &Bs[c][0][0];
    bf16x8 af[4], bfr[4];

    // ---- phase 1: khalf 0, C-half 0; prefetch (T+1).A-k1 -> buf c^1 ----
#pragma unroll
    for (int j = 0; j < 4; ++j) bfr[j] = *(const bf16x8*)&Bc[baseB + j * 512];
#pragma unroll
    for (int i = 0; i < 4; ++i) af[i] = *(const bf16x8*)&Ac[baseA + i * 512];
    if (T + 1 < NT) stA(T + 1, 1, c ^ 1);
    asm volatile("s_barrier" ::: "memory");
    __builtin_amdgcn_s_setprio(1);
#pragma unroll
    for (int i = 0; i < 4; ++i)
#pragma unroll
      for (int j = 0; j < 4; ++j)
        acc[i][j] = __builtin_amdgcn_mfma_f32_16x16x32_bf16(af[i], bfr[j], acc[i][j], 0, 0, 0);
    __builtin_amdgcn_s_setprio(0);
    asm volatile("s_barrier" ::: "memory");

    // ---- phase 2: khalf 0, C-half 1 (reuse B frags); prefetch (T+1).B-k1 ----
#pragma unroll
    for (int i = 0; i < 4; ++i) af[i] = *(const bf16x8*)&Ac[baseA + 2048 + i * 512];
    if (T + 1 < NT) stB(T + 1, 1, c ^ 1);
    asm volatile("s_barrier" ::: "memory");
    __builtin_amdgcn_s_setprio(1);
#pragma unroll
    for (int i = 0; i < 4; ++i)
#pragma unroll
      for (int j = 0; j < 4; ++j)
        acc[4 + i][j] = __builtin_amdgcn_mfma_f32_16x16x32_bf16(af[i], bfr[j], acc[4 + i][j], 0, 0, 0);
    __builtin_amdgcn_s_setprio(0);
    asm volatile("s_barrier" ::: "memory");

    // ---- phase 3: khalf 1, C-half 0; prefetch (T+2).A-k0 -> buf c (its k0 reads
    // finished at phase 2's closing barrier). Last tile: drain own k1 loads.
    if (T == NT - 1) {
      asm volatile("s_waitcnt vmcnt(0)" ::: "memory");
      asm volatile("s_barrier" ::: "memory");
    }
#pragma unroll
    for (int j = 0; j < 4; ++j) bfr[j] = *(const bf16x8*)&Bc[8192 + baseB + j * 512];
#pragma unroll
    for (int i = 0; i < 4; ++i) af[i] = *(const bf16x8*)&Ac[8192 + baseA + i * 512];
    if (T + 2 < NT) stA(T + 2, 0, c);
    asm volatile("s_barrier" ::: "memory");
    __builtin_amdgcn_s_setprio(1);
#pragma unroll
    for (int i = 0; i < 4; ++i)
#pragma unroll
      for (int j = 0; j < 4; ++j)
        acc[i][j] = __builtin_amdgcn_mfma_f32_16x16x32_bf16(af[i], bfr[j], acc[i][j], 0, 0, 0);
    __builtin_amdgcn_s_setprio(0);
    asm volatile("s_barrier" ::: "memory");

    // ---- phase 4: khalf 1, C-half 1; prefetch (T+2).B-k0; tile gate vmcnt(4) ----
#pragma unroll
    for (int i = 0; i < 4; ++i) af[i] = *(const bf16x8*)&Ac[8192 + baseA + 2048 + i * 512];
    if (T + 2 < NT) stB(T + 2, 0, c);
    asm volatile("s_barrier" ::: "memory");
    __builtin_amdgcn_s_setprio(1);
#pragma unroll
    for (int i = 0; i < 4; ++i)
#pragma unroll
      for (int j = 0; j < 4; ++j)
        acc[4 + i][j] = __builtin_amdgcn_mfma_f32_16x16x32_bf16(af[i], bfr[j], acc[4 + i][j], 0, 0, 0);
    __builtin_amdgcn_s_setprio(0);
    asm volatile("s_waitcnt vmcnt(4)" ::: "memory");   // counted gate: next tile ready,
    asm volatile("s_barrier" ::: "memory");            // 2 half-tiles stay in flight
  }

  float cb[4];
  if (!rowbias) {
#pragma unroll
    for (int j = 0; j < 4; ++j) cb[j] = bias[n0 + wc * 64 + j * 16 + l15];
  }

#pragma unroll
  for (int mf = 0; mf < 8; ++mf) {
#pragma unroll
    for (int r = 0; r < 4; ++r) {
      int row = m0 + wr * 128 + mf * 16 + quad * 4 + r;
      long base = (long)row * ldc + n0 + wc * 64;
      float rb_ = rowbias ? bias[row] : 0.f;
#pragma unroll
      for (int j = 0; j < 4; ++j) {
        float v = acc[mf][j][r] + (rowbias ? rb_ : cb[j]);
        if (STORE_BF16) ((u16*)Cout)[base + j * 16 + l15] = f2bf(v);
        else            ((float*)Cout)[base + j * 16 + l15] = v;
      }
    }
  }
}

// ---------------------------------------------------------------- fused QKV + V^T GEMM
// 192 blocks: Q 16x4, K 16x4, V^T 4x16 in 256x256 tiles. XCD-chunked remap
// (192 % 8 == 0 -> bijective): consecutive logical tiles share an XCD L2.
__global__ __launch_bounds__(512, 2) void gemm_qkv(
    const u16* __restrict__ xb, const u16* __restrict__ wqb,
    const u16* __restrict__ wkb, const u16* __restrict__ wvb,
    const float* __restrict__ bq, const float* __restrict__ bk,
    const float* __restrict__ bv,
    u16* __restrict__ Qb, u16* __restrict__ Kb, u16* __restrict__ Vtg) {
  const int bx = blockIdx.x;
  const int L = (bx & 7) * 24 + (bx >> 3);
  const u16 *AT, *BT;
  const float* bias;
  u16* C;
  int m0, n0, ldc;
  bool rowbias;
  if (L < 128) {
    int sel = L >> 6;      // 0 = Q, 1 = K
    int g = L & 63;
    m0 = (g >> 2) * 256; n0 = (g & 3) * 256;
    AT = xb; BT = sel ? wkb : wqb; bias = sel ? bk : bq;
    C = sel ? Kb : Qb; ldc = 1024; rowbias = false;
  } else {
    int g = L - 128;
    m0 = (g & 3) * 256; n0 = (g >> 2) * 256;
    AT = wvb; BT = xb; bias = bv;
    C = Vtg; ldc = 4096; rowbias = true;
  }
  gemm256_body<true>(AT, BT, bias, rowbias, C, ldc, m0, n0);
}

// ---------------------------------------------------------------- output GEMM
__global__ __launch_bounds__(256) void gemm_out(
    const u16* __restrict__ A, const u16* __restrict__ B,
    const float* __restrict__ bias, float* __restrict__ C) {
  gemm_body<false>(A, B, bias, false, C, 1024, blockIdx.x * 128, blockIdx.y * 128);
}

// ---------------------------------------------------------------- attention
// 512 threads = 8 waves; block = (b,h, 128-row q-strip). strip = 7 - (bx>>6) (LPT:
// longest chains dispatch first), bh = bx & 63. Wave wv owns q rows
// strip*128 + wv*16 .. +15. Chunks 0..2*strip+1; fast path (const clipped bias,
// mask-free) for c <= 2*strip-2. S^T MFMA + b64 Ws spill + swizzled K/V LDS
// (all mechanisms HW-verified: conflicts = 0). Output in-place over Qb.
__global__ __launch_bounds__(512) void attn_strip(
    const u16* __restrict__ Qb,     // [4096][1024]
    const u16* __restrict__ Kb,     // [4096][1024]
    const u16* __restrict__ Vtg,    // [1024][4096] V^T
    const float* __restrict__ rel_bias,  // [63][16]
    u16* __restrict__ att) {        // == Qb
  constexpr int WS = 68;
  __shared__ __align__(16) u16 Kt[64 * 64];
  __shared__ __align__(16) u16 Vt[64 * 64];
  __shared__ __align__(16) u16 Ws[8][16 * WS];
  __shared__ float biasl[64];

  const int bx = blockIdx.x;
  const int strip = 7 - (bx >> 6);
  const int bh = bx & 63;
  const int b = bh >> 4, h = bh & 15;
  const int q0 = strip * 128;
  const int cend = 2 * strip + 1;

  const int t = threadIdx.x;
  const int lane = t & 63;
  const int wv = t >> 6;          // 0..7
  const int quad = lane >> 4;
  const int l15 = lane & 15;

  if (t < 63) biasl[t] = rel_bias[t * 16 + h];
  const float b0c = rel_bias[h];  // clipped bias for dd <= -31

  // Q fragments: wave's 16 q-rows (A/B-operand layout)
  const long qrow = (long)(b * 1024 + q0 + wv * 16 + l15) * 1024 + h * 64;
  bf16x8 qf0 = *(const bf16x8*)&Qb[qrow + quad * 8];
  bf16x8 qf1 = *(const bf16x8*)&Qb[qrow + 32 + quad * 8];

  const f32x4 vzero = {0.f, 0.f, 0.f, 0.f};
  f32x4 acc_o[4];
#pragma unroll
  for (int j = 0; j < 4; ++j) acc_o[j] = vzero;
  float denom = 0.f;
  const float scale = 0.125f;  // 64^-0.5
  const int ql = q0 + wv * 16 + l15;
  const int sw0 = (quad ^ (l15 & 7)) * 8;
  const int sw1 = ((4 + quad) ^ (l15 & 7)) * 8;

  for (int c = 0; c <= cend; ++c) {
    const int k0 = c * 64;
    if (c) __syncthreads();
    // stage K [key][d] and V^T [d][key]: 512 granules each, 1 per thread
    {
      int row = t >> 3, seg = t & 7;
      int sw = row * 64 + ((seg ^ (row & 7)) * 8);
      uint4 kv = *(const uint4*)&Kb[(long)(b * 1024 + k0 + row) * 1024 + h * 64 + seg * 8];
      uint4 vvl = *(const uint4*)&Vtg[(long)(h * 64 + row) * 4096 + b * 1024 + k0 + seg * 8];
      *(uint4*)&Kt[sw] = kv;
      *(uint4*)&Vt[sw] = vvl;
    }
    __syncthreads();

    const bool fast = (c <= 2 * strip - 2);
#pragma unroll
    for (int g = 0; g < 4; ++g) {
      const u16* kr = &Kt[(g * 16 + l15) * 64];
      bf16x8 kf0 = *(const bf16x8*)&kr[sw0];
      bf16x8 kf1 = *(const bf16x8*)&kr[sw1];
      f32x4 sT = vzero;
      sT = __builtin_amdgcn_mfma_f32_16x16x32_bf16(kf0, qf0, sT, 0, 0, 0);
      sT = __builtin_amdgcn_mfma_f32_16x16x32_bf16(kf1, qf1, sT, 0, 0, 0);
      const int kgb = k0 + g * 16 + quad * 4;
      ushort4 wpk;
      if (fast) {
#pragma unroll
        for (int r = 0; r < 4; ++r) {
          float w = fmaxf(sT[r] * scale + b0c, 0.f) + 1e-6f;
          u16 wb = f2bf(w);
          denom += bf2f(wb);
          ((u16*)&wpk)[r] = wb;
        }
      } else {
#pragma unroll
        for (int r = 0; r < 4; ++r) {
          int kg = kgb + r;
          int dd = kg - ql;
          dd = dd < -31 ? -31 : (dd > 31 ? 31 : dd);
          float sv = sT[r] * scale + biasl[dd + 31];
          float w = (kg <= ql) ? (fmaxf(sv, 0.f) + 1e-6f) : 0.f;
          u16 wb = f2bf(w);
          denom += bf2f(wb);
          ((u16*)&wpk)[r] = wb;
        }
      }
      *(ushort4*)&Ws[wv][l15 * WS + g * 16 + quad * 4] = wpk;
    }
    asm volatile("s_waitcnt lgkmcnt(0)" ::: "memory");   // Ws wave-private W->R
#pragma unroll
    for (int ks = 0; ks < 64; ks += 32) {
      union { bf16x8 v8; bf16x4 v4[2]; } au;
      int wbase = l15 * WS + ks + quad * 8;
      au.v4[0] = *(const bf16x4*)&Ws[wv][wbase];
      au.v4[1] = *(const bf16x4*)&Ws[wv][wbase + 4];
      const int sv = ks ? sw1 : sw0;
#pragma unroll
      for (int j = 0; j < 4; ++j) {
        bf16x8 bvv = *(const bf16x8*)&Vt[(j * 16 + l15) * 64 + sv];
        acc_o[j] = __builtin_amdgcn_mfma_f32_16x16x32_bf16(au.v8, bvv, acc_o[j], 0, 0, 0);
      }
    }
  }

  // denom for q=l15: reduce across the 4 quads
  denom += __shfl_xor(denom, 16);
  denom += __shfl_xor(denom, 32);

  float invm = 1.f / (denom + 1e-6f);
  float inv[4];
#pragma unroll
  for (int r = 0; r < 4; ++r) inv[r] = __shfl(invm, quad * 4 + r);
#pragma unroll
  for (int j = 0; j < 4; ++j)
#pragma unroll
    for (int r = 0; r < 4; ++r) {
      int q = q0 + wv * 16 + quad * 4 + r;
      att[(long)(b * 1024 + q) * 1024 + h * 64 + j * 16 + l15] = f2bf(acc_o[j][r] * inv[r]);
    }
}

// ---------------------------------------------------------------- launch
extern "C" void kernel_launch(void* const* d_in, const int* in_sizes, int n_in,
                              void* d_out, int out_size, void* d_ws, size_t ws_size,
                              hipStream_t stream) {
  const float* x  = (const float*)d_in[0];
  const float* Wq = (const float*)d_in[2];
  const float* bq = (const float*)d_in[3];
  const float* Wk = (const float*)d_in[4];
  const float* bk = (const float*)d_in[5];
  const float* Wv = (const float*)d_in[6];
  const float* bv = (const float*)d_in[7];
  const float* Wo = (const float*)d_in[8];
  const float* bo = (const float*)d_in[9];
  const float* rb = (const float*)d_in[10];

  char* ws = (char*)d_ws;
  u16* xb  = (u16*)(ws);
  u16* wqb = (u16*)(ws + (8l  << 20));
  u16* wkb = (u16*)(ws + (10l << 20));
  u16* wvb = (u16*)(ws + (12l << 20));
  u16* wob = (u16*)(ws + (14l << 20));
  u16* Qb  = (u16*)(ws + (16l << 20));
  u16* Kb  = (u16*)d_out;
  u16* Vtg = (u16*)((char*)d_out + (8l << 20));

  cast_all_kernel<<<8192, 256, 0, stream>>>(x, Wq, Wk, Wv, Wo, xb, wqb, wkb, wvb, wob);
  gemm_qkv<<<192, 512, 0, stream>>>(xb, wqb, wkb, wvb, bq, bk, bv, Qb, Kb, Vtg);
  attn_strip<<<512, 512, 0, stream>>>(Qb, Kb, Vtg, rb, Qb);
  gemm_out<<<dim3(32, 8), 256, 0, stream>>>(Qb, wob, bo, (float*)d_out);
}

// Round 2
// 183.810 us; speedup vs baseline: 1.0402x; 1.0144x over previous
//
#include <hip/hip_runtime.h>

// AlgebraicAttention on MI355X (gfx950), round 12.
// R11 post-mortem: gemm_qkv 44us = 783 TF on active CUs ~= the m248 K=1024
// 8-phase ceiling (848 TF); residual is 192/256 grid fill with no clean pow-2
// fix -> gemm_qkv parked. This round: attn_strip staging was
// barrier -> reg-stage K/V -> barrier -> compute: ~600-900cy global latency
// exposed EVERY chunk (T14/m177 regime). Fix: double-buffered K/V LDS staged
// via global_load_lds (pre-swizzled SOURCE + linear dest, rule #21; same LDS
// layout as before, reads untouched), stage(c+1) issued right after the single
// per-chunk __syncthreads (its implicit vmcnt(0) drains the chunk-earlier
// stage -> latency hidden under compute). 2 barriers/chunk -> 1. All math and
// every other kernel byte-identical to r11.
// ws: [0,8M) xb | [8,10M) wqb | [10,12M) wkb | [12,14M) wvb | [14,16M) wob |
//     [16,24M) Qb (att in-place). d_out: [0,8M) Kb | [8,16M) Vtg (V^T).

typedef __attribute__((ext_vector_type(8))) __bf16 bf16x8;
typedef __attribute__((ext_vector_type(4))) __bf16 bf16x4;
typedef __attribute__((ext_vector_type(4))) float f32x4;
typedef unsigned short u16;

__device__ __forceinline__ u16 f2bf(float f) {
  unsigned u = __float_as_uint(f);
  u += 0x7FFFu + ((u >> 16) & 1u);   // round-to-nearest-even
  return (u16)(u >> 16);
}
__device__ __forceinline__ float bf2f(u16 b) {
  return __uint_as_float(((unsigned)b) << 16);
}
__device__ __forceinline__ void gl_lds16(const void* g, void* l) {
  __builtin_amdgcn_global_load_lds((__attribute__((address_space(1))) void*)g,
                                   (__attribute__((address_space(3))) void*)l,
                                   16, 0, 0);
}

// ---------------------------------------------------------------- cast kernel
__global__ __launch_bounds__(256) void cast_all_kernel(
    const float* __restrict__ x,  const float* __restrict__ wq,
    const float* __restrict__ wk, const float* __restrict__ wv,
    const float* __restrict__ wo,
    u16* __restrict__ xb, u16* __restrict__ wqb, u16* __restrict__ wkb,
    u16* __restrict__ wvb, u16* __restrict__ wob) {
  long i4 = (long)blockIdx.x * 256 + threadIdx.x;
  const float* src; u16* dst; long rel;
  if (i4 < 1048576) { src = x; dst = xb; rel = i4; }
  else {
    long j = i4 - 1048576;
    int w = (int)(j >> 18);
    rel = j & 262143;
    src = (w == 0) ? wq : (w == 1) ? wk : (w == 2) ? wv : wo;
    dst = (w == 0) ? wqb : (w == 1) ? wkb : (w == 2) ? wvb : wob;
  }
  float4 v = ((const float4*)src)[rel];
  ushort4 o;
  o.x = f2bf(v.x); o.y = f2bf(v.y); o.z = f2bf(v.z); o.w = f2bf(v.w);
  ((ushort4*)dst)[rel] = o;
}

// ---------------------------------------------------------------- GEMM body (r9, proven)
// C = A @ B^T (+bias). 128x128 tile, BK=64, double-buffered swizzled LDS,
// raw s_barrier + vmcnt(8) pipeline. Kept for gemm_out (256 full-fill blocks).
template <bool STORE_BF16>
__device__ __forceinline__ void gemm_body(
    const u16* __restrict__ A, const u16* __restrict__ B,
    const float* __restrict__ bias, bool rowbias,
    void* __restrict__ Cout, int ldc, int m0, int n0) {
  constexpr int K = 1024;
  constexpr int NT = K / 64;
  __shared__ __align__(16) u16 As[2][128 * 64];
  __shared__ __align__(16) u16 Bs[2][128 * 64];

  const int t = threadIdx.x;
  const int lane = t & 63;
  const int wv = t >> 6;
  const int quad = lane >> 4;
  const int l15 = lane & 15;
  const int wr = wv >> 1, wc = wv & 1;
  const int sw0 = (quad ^ (l15 & 7)) * 8;
  const int sw1 = ((4 + quad) ^ (l15 & 7)) * 8;

  const f32x4 vzero = {0.f, 0.f, 0.f, 0.f};
  f32x4 acc[4][4];
#pragma unroll
  for (int i = 0; i < 4; ++i)
#pragma unroll
    for (int j = 0; j < 4; ++j) acc[i][j] = vzero;

  auto stage = [&](int kt, int bufi) {
#pragma unroll
    for (int p = 0; p < 4; ++p) {
      int idx = t + p * 256;
      int row = idx >> 3, seg = idx & 7;
      int sseg = seg ^ (row & 7);
      gl_lds16(&A[(long)(m0 + row) * K + kt * 64 + sseg * 8], &As[bufi][idx * 8]);
      gl_lds16(&B[(long)(n0 + row) * K + kt * 64 + sseg * 8], &Bs[bufi][idx * 8]);
    }
  };

  stage(0, 0);
  for (int kt = 0; kt < NT; ++kt) {
    const int bufi = kt & 1;
    if (kt + 1 < NT) {
      stage(kt + 1, bufi ^ 1);
      asm volatile("s_waitcnt vmcnt(8)" ::: "memory");
    } else {
      asm volatile("s_waitcnt vmcnt(0)" ::: "memory");
    }
    asm volatile("s_barrier" ::: "memory");
#pragma unroll
    for (int ks = 0; ks < 64; ks += 32) {
      const int sw = ks ? sw1 : sw0;
      bf16x8 af[4], bfg[4];
#pragma unroll
      for (int i = 0; i < 4; ++i)
        af[i] = *(const bf16x8*)&As[bufi][(wr * 64 + i * 16 + l15) * 64 + sw];
#pragma unroll
      for (int j = 0; j < 4; ++j)
        bfg[j] = *(const bf16x8*)&Bs[bufi][(wc * 64 + j * 16 + l15) * 64 + sw];
#pragma unroll
      for (int i = 0; i < 4; ++i)
#pragma unroll
        for (int j = 0; j < 4; ++j)
          acc[i][j] = __builtin_amdgcn_mfma_f32_16x16x32_bf16(af[i], bfg[j], acc[i][j], 0, 0, 0);
    }
    asm volatile("s_barrier" ::: "memory");
  }

  float cb[4];
  if (!rowbias) {
#pragma unroll
    for (int j = 0; j < 4; ++j) cb[j] = bias[n0 + wc * 64 + j * 16 + l15];
  }

#pragma unroll
  for (int i = 0; i < 4; ++i) {
#pragma unroll
    for (int r = 0; r < 4; ++r) {
      int row = m0 + wr * 64 + i * 16 + quad * 4 + r;
      long base = (long)row * ldc + n0 + wc * 64;
      float rb_ = rowbias ? bias[row] : 0.f;
#pragma unroll
      for (int j = 0; j < 4; ++j) {
        float v = acc[i][j][r] + (rowbias ? rb_ : cb[j]);
        if (STORE_BF16) ((u16*)Cout)[base + j * 16 + l15] = f2bf(v);
        else            ((float*)Cout)[base + j * 16 + l15] = v;
      }
    }
  }
}

// ---------------------------------------------------------------- 256x256 8-phase body
// C = A @ B^T (+bias). BK=64 split into two K-halves of 32. 8 waves (2M x 4N),
// per-wave C = 128x64 (acc[8][4]). LDS: [buf][khalf][256 rows][32 cols] per operand.
// Granule swizzle gs = g ^ ((row>>1)&3): pre-swizzled global source, linear LDS
// dest (global_load_lds requirement), swizzled ds_read -> 2-way max (free).
// Measured r11: 783 TF on active CUs ~= m248's K=1024 ceiling. Parked.
template <bool STORE_BF16>
__device__ __forceinline__ void gemm256_body(
    const u16* __restrict__ A, const u16* __restrict__ B,
    const float* __restrict__ bias, bool rowbias,
    void* __restrict__ Cout, int ldc, int m0, int n0) {
  constexpr int K = 1024;
  constexpr int NT = K / 64;      // 16 K-tiles
  __shared__ __align__(16) u16 As[2][2][256 * 32];  // 64 KiB
  __shared__ __align__(16) u16 Bs[2][2][256 * 32];  // 64 KiB

  const int t = threadIdx.x;      // 0..511
  const int lane = t & 63;
  const int wv = t >> 6;          // 0..7
  const int wr = wv >> 2;         // 0..1  (M-half of C)
  const int wc = wv & 3;          // 0..3  (N quarter)
  const int quad = lane >> 4;
  const int l15 = lane & 15;

  const int rA = wr * 128 + l15;
  const int rB = wc * 64 + l15;
  const int baseA = rA * 32 + ((quad ^ ((rA >> 1) & 3)) * 8);
  const int baseB = rB * 32 + ((quad ^ ((rB >> 1) & 3)) * 8);

  const int srow = t >> 2;
  const int sg = (t & 3) ^ ((t >> 3) & 3);
  const long sA = (long)(m0 + srow) * K + sg * 8;
  const long sB = (long)(n0 + srow) * K + sg * 8;

  auto stA = [&](int T_, int kh, int bf_) {
    const u16* s = A + sA + T_ * 64 + kh * 32;
    u16* d = &As[bf_][kh][t * 8];
    gl_lds16(s, d);
    gl_lds16(s + (long)128 * K, d + 4096);
  };
  auto stB = [&](int T_, int kh, int bf_) {
    const u16* s = B + sB + T_ * 64 + kh * 32;
    u16* d = &Bs[bf_][kh][t * 8];
    gl_lds16(s, d);
    gl_lds16(s + (long)128 * K, d + 4096);
  };

  const f32x4 vzero = {0.f, 0.f, 0.f, 0.f};
  f32x4 acc[8][4];
#pragma unroll
  for (int i = 0; i < 8; ++i)
#pragma unroll
    for (int j = 0; j < 4; ++j) acc[i][j] = vzero;

  stA(0, 0, 0); stB(0, 0, 0);
  stA(0, 1, 0); stB(0, 1, 0);
  stA(1, 0, 1); stB(1, 0, 1);
  asm volatile("s_waitcnt vmcnt(4)" ::: "memory");
  asm volatile("s_barrier" ::: "memory");

  for (int T = 0; T < NT; ++T) {
    const int c = T & 1;
    const u16* Ac = &As[c][0][0];
    const u16* Bc = &Bs[c][0][0];
    bf16x8 af[4], bfr[4];

    // ---- phase 1: khalf 0, C-half 0; prefetch (T+1).A-k1 -> buf c^1 ----
#pragma unroll
    for (int j = 0; j < 4; ++j) bfr[j] = *(const bf16x8*)&Bc[baseB + j * 512];
#pragma unroll
    for (int i = 0; i < 4; ++i) af[i] = *(const bf16x8*)&Ac[baseA + i * 512];
    if (T + 1 < NT) stA(T + 1, 1, c ^ 1);
    asm volatile("s_barrier" ::: "memory");
    __builtin_amdgcn_s_setprio(1);
#pragma unroll
    for (int i = 0; i < 4; ++i)
#pragma unroll
      for (int j = 0; j < 4; ++j)
        acc[i][j] = __builtin_amdgcn_mfma_f32_16x16x32_bf16(af[i], bfr[j], acc[i][j], 0, 0, 0);
    __builtin_amdgcn_s_setprio(0);
    asm volatile("s_barrier" ::: "memory");

    // ---- phase 2: khalf 0, C-half 1 (reuse B frags); prefetch (T+1).B-k1 ----
#pragma unroll
    for (int i = 0; i < 4; ++i) af[i] = *(const bf16x8*)&Ac[baseA + 2048 + i * 512];
    if (T + 1 < NT) stB(T + 1, 1, c ^ 1);
    asm volatile("s_barrier" ::: "memory");
    __builtin_amdgcn_s_setprio(1);
#pragma unroll
    for (int i = 0; i < 4; ++i)
#pragma unroll
      for (int j = 0; j < 4; ++j)
        acc[4 + i][j] = __builtin_amdgcn_mfma_f32_16x16x32_bf16(af[i], bfr[j], acc[4 + i][j], 0, 0, 0);
    __builtin_amdgcn_s_setprio(0);
    asm volatile("s_barrier" ::: "memory");

    // ---- phase 3: khalf 1, C-half 0; prefetch (T+2).A-k0 -> buf c ----
    if (T == NT - 1) {
      asm volatile("s_waitcnt vmcnt(0)" ::: "memory");
      asm volatile("s_barrier" ::: "memory");
    }
#pragma unroll
    for (int j = 0; j < 4; ++j) bfr[j] = *(const bf16x8*)&Bc[8192 + baseB + j * 512];
#pragma unroll
    for (int i = 0; i < 4; ++i) af[i] = *(const bf16x8*)&Ac[8192 + baseA + i * 512];
    if (T + 2 < NT) stA(T + 2, 0, c);
    asm volatile("s_barrier" ::: "memory");
    __builtin_amdgcn_s_setprio(1);
#pragma unroll
    for (int i = 0; i < 4; ++i)
#pragma unroll
      for (int j = 0; j < 4; ++j)
        acc[i][j] = __builtin_amdgcn_mfma_f32_16x16x32_bf16(af[i], bfr[j], acc[i][j], 0, 0, 0);
    __builtin_amdgcn_s_setprio(0);
    asm volatile("s_barrier" ::: "memory");

    // ---- phase 4: khalf 1, C-half 1; prefetch (T+2).B-k0; tile gate vmcnt(4) ----
#pragma unroll
    for (int i = 0; i < 4; ++i) af[i] = *(const bf16x8*)&Ac[8192 + baseA + 2048 + i * 512];
    if (T + 2 < NT) stB(T + 2, 0, c);
    asm volatile("s_barrier" ::: "memory");
    __builtin_amdgcn_s_setprio(1);
#pragma unroll
    for (int i = 0; i < 4; ++i)
#pragma unroll
      for (int j = 0; j < 4; ++j)
        acc[4 + i][j] = __builtin_amdgcn_mfma_f32_16x16x32_bf16(af[i], bfr[j], acc[4 + i][j], 0, 0, 0);
    __builtin_amdgcn_s_setprio(0);
    asm volatile("s_waitcnt vmcnt(4)" ::: "memory");
    asm volatile("s_barrier" ::: "memory");
  }

  float cb[4];
  if (!rowbias) {
#pragma unroll
    for (int j = 0; j < 4; ++j) cb[j] = bias[n0 + wc * 64 + j * 16 + l15];
  }

#pragma unroll
  for (int mf = 0; mf < 8; ++mf) {
#pragma unroll
    for (int r = 0; r < 4; ++r) {
      int row = m0 + wr * 128 + mf * 16 + quad * 4 + r;
      long base = (long)row * ldc + n0 + wc * 64;
      float rb_ = rowbias ? bias[row] : 0.f;
#pragma unroll
      for (int j = 0; j < 4; ++j) {
        float v = acc[mf][j][r] + (rowbias ? rb_ : cb[j]);
        if (STORE_BF16) ((u16*)Cout)[base + j * 16 + l15] = f2bf(v);
        else            ((float*)Cout)[base + j * 16 + l15] = v;
      }
    }
  }
}

// ---------------------------------------------------------------- fused QKV + V^T GEMM
__global__ __launch_bounds__(512, 2) void gemm_qkv(
    const u16* __restrict__ xb, const u16* __restrict__ wqb,
    const u16* __restrict__ wkb, const u16* __restrict__ wvb,
    const float* __restrict__ bq, const float* __restrict__ bk,
    const float* __restrict__ bv,
    u16* __restrict__ Qb, u16* __restrict__ Kb, u16* __restrict__ Vtg) {
  const int bx = blockIdx.x;
  const int L = (bx & 7) * 24 + (bx >> 3);
  const u16 *AT, *BT;
  const float* bias;
  u16* C;
  int m0, n0, ldc;
  bool rowbias;
  if (L < 128) {
    int sel = L >> 6;      // 0 = Q, 1 = K
    int g = L & 63;
    m0 = (g >> 2) * 256; n0 = (g & 3) * 256;
    AT = xb; BT = sel ? wkb : wqb; bias = sel ? bk : bq;
    C = sel ? Kb : Qb; ldc = 1024; rowbias = false;
  } else {
    int g = L - 128;
    m0 = (g & 3) * 256; n0 = (g >> 2) * 256;
    AT = wvb; BT = xb; bias = bv;
    C = Vtg; ldc = 4096; rowbias = true;
  }
  gemm256_body<true>(AT, BT, bias, rowbias, C, ldc, m0, n0);
}

// ---------------------------------------------------------------- output GEMM
__global__ __launch_bounds__(256) void gemm_out(
    const u16* __restrict__ A, const u16* __restrict__ B,
    const float* __restrict__ bias, float* __restrict__ C) {
  gemm_body<false>(A, B, bias, false, C, 1024, blockIdx.x * 128, blockIdx.y * 128);
}

// ---------------------------------------------------------------- attention
// 512 threads = 8 waves; block = (b,h, 128-row q-strip). strip = 7 - (bx>>6) (LPT),
// bh = bx & 63. Wave wv owns q rows strip*128 + wv*16 .. +15. Chunks 0..2*strip+1;
// fast path (const clipped bias, mask-free) for c <= 2*strip-2.
// r12: K/V staged via global_load_lds into double buffers; pre-swizzled global
// source + linear LDS dest reproduces the old swizzled layout exactly (reads
// unchanged, conflicts stay 0). stage(c+1) issued right after the single
// per-chunk __syncthreads (implicit vmcnt(0) drains the chunk-earlier stage) ->
// global latency hidden under QK^T/softmax/PV. Output in-place over Qb.
__global__ __launch_bounds__(512) void attn_strip(
    const u16* __restrict__ Qb,     // [4096][1024]
    const u16* __restrict__ Kb,     // [4096][1024]
    const u16* __restrict__ Vtg,    // [1024][4096] V^T
    const float* __restrict__ rel_bias,  // [63][16]
    u16* __restrict__ att) {        // == Qb
  constexpr int WS = 68;
  __shared__ __align__(16) u16 Kt[2][64 * 64];
  __shared__ __align__(16) u16 Vt[2][64 * 64];
  __shared__ __align__(16) u16 Ws[8][16 * WS];
  __shared__ float biasl[64];

  const int bx = blockIdx.x;
  const int strip = 7 - (bx >> 6);
  const int bh = bx & 63;
  const int b = bh >> 4, h = bh & 15;
  const int q0 = strip * 128;
  const int cend = 2 * strip + 1;

  const int t = threadIdx.x;
  const int lane = t & 63;
  const int wv = t >> 6;          // 0..7
  const int quad = lane >> 4;
  const int l15 = lane & 15;

  if (t < 63) biasl[t] = rel_bias[t * 16 + h];
  const float b0c = rel_bias[h];  // clipped bias for dd <= -31

  // staging: thread t -> LDS row srow = t>>3, linear granule t&7; global source
  // granule pre-swizzled by (srow&7) so LDS content matches the old swizzled
  // layout: LDS[row][s] = src[row][s ^ (row&7)].
  const int srow = t >> 3;
  const int sseg = (t & 7) ^ (srow & 7);
  const u16* Ksrc = &Kb[(long)(b * 1024 + srow) * 1024 + h * 64 + sseg * 8];
  const u16* Vsrc = &Vtg[(long)(h * 64 + srow) * 4096 + b * 1024 + sseg * 8];

  auto stage = [&](int c, int bufi) {
    const int k0 = c * 64;
    gl_lds16(Ksrc + (long)k0 * 1024, &Kt[bufi][t * 8]);
    gl_lds16(Vsrc + k0,              &Vt[bufi][t * 8]);
  };

  // Q fragments: wave's 16 q-rows (A/B-operand layout)
  const long qrow = (long)(b * 1024 + q0 + wv * 16 + l15) * 1024 + h * 64;
  bf16x8 qf0 = *(const bf16x8*)&Qb[qrow + quad * 8];
  bf16x8 qf1 = *(const bf16x8*)&Qb[qrow + 32 + quad * 8];

  const f32x4 vzero = {0.f, 0.f, 0.f, 0.f};
  f32x4 acc_o[4];
#pragma unroll
  for (int j = 0; j < 4; ++j) acc_o[j] = vzero;
  float denom = 0.f;
  const float scale = 0.125f;  // 64^-0.5
  const int ql = q0 + wv * 16 + l15;
  const int sw0 = (quad ^ (l15 & 7)) * 8;
  const int sw1 = ((4 + quad) ^ (l15 & 7)) * 8;

  stage(0, 0);   // drained by the first __syncthreads below

  for (int c = 0; c <= cend; ++c) {
    const int buf = c & 1;
    const int k0 = c * 64;
    // drains stage(c) (implicit vmcnt(0)+lgkmcnt(0)); also fences biasl (c=0)
    // and releases buf^1 (its chunk c-1 readers all retired before this point).
    __syncthreads();
    if (c + 1 <= cend) stage(c + 1, buf ^ 1);

    const bool fast = (c <= 2 * strip - 2);
#pragma unroll
    for (int g = 0; g < 4; ++g) {
      const u16* kr = &Kt[buf][(g * 16 + l15) * 64];
      bf16x8 kf0 = *(const bf16x8*)&kr[sw0];
      bf16x8 kf1 = *(const bf16x8*)&kr[sw1];
      f32x4 sT = vzero;
      sT = __builtin_amdgcn_mfma_f32_16x16x32_bf16(kf0, qf0, sT, 0, 0, 0);
      sT = __builtin_amdgcn_mfma_f32_16x16x32_bf16(kf1, qf1, sT, 0, 0, 0);
      const int kgb = k0 + g * 16 + quad * 4;
      ushort4 wpk;
      if (fast) {
#pragma unroll
        for (int r = 0; r < 4; ++r) {
          float w = fmaxf(sT[r] * scale + b0c, 0.f) + 1e-6f;
          u16 wb = f2bf(w);
          denom += bf2f(wb);
          ((u16*)&wpk)[r] = wb;
        }
      } else {
#pragma unroll
        for (int r = 0; r < 4; ++r) {
          int kg = kgb + r;
          int dd = kg - ql;
          dd = dd < -31 ? -31 : (dd > 31 ? 31 : dd);
          float sv = sT[r] * scale + biasl[dd + 31];
          float w = (kg <= ql) ? (fmaxf(sv, 0.f) + 1e-6f) : 0.f;
          u16 wb = f2bf(w);
          denom += bf2f(wb);
          ((u16*)&wpk)[r] = wb;
        }
      }
      *(ushort4*)&Ws[wv][l15 * WS + g * 16 + quad * 4] = wpk;
    }
    asm volatile("s_waitcnt lgkmcnt(0)" ::: "memory");   // Ws wave-private W->R
#pragma unroll
    for (int ks = 0; ks < 64; ks += 32) {
      union { bf16x8 v8; bf16x4 v4[2]; } au;
      int wbase = l15 * WS + ks + quad * 8;
      au.v4[0] = *(const bf16x4*)&Ws[wv][wbase];
      au.v4[1] = *(const bf16x4*)&Ws[wv][wbase + 4];
      const int sv = ks ? sw1 : sw0;
#pragma unroll
      for (int j = 0; j < 4; ++j) {
        bf16x8 bvv = *(const bf16x8*)&Vt[buf][(j * 16 + l15) * 64 + sv];
        acc_o[j] = __builtin_amdgcn_mfma_f32_16x16x32_bf16(au.v8, bvv, acc_o[j], 0, 0, 0);
      }
    }
  }

  // denom for q=l15: reduce across the 4 quads
  denom += __shfl_xor(denom, 16);
  denom += __shfl_xor(denom, 32);

  float invm = 1.f / (denom + 1e-6f);
  float inv[4];
#pragma unroll
  for (int r = 0; r < 4; ++r) inv[r] = __shfl(invm, quad * 4 + r);
#pragma unroll
  for (int j = 0; j < 4; ++j)
#pragma unroll
    for (int r = 0; r < 4; ++r) {
      int q = q0 + wv * 16 + quad * 4 + r;
      att[(long)(b * 1024 + q) * 1024 + h * 64 + j * 16 + l15] = f2bf(acc_o[j][r] * inv[r]);
    }
}

// ---------------------------------------------------------------- launch
extern "C" void kernel_launch(void* const* d_in, const int* in_sizes, int n_in,
                              void* d_out, int out_size, void* d_ws, size_t ws_size,
                              hipStream_t stream) {
  const float* x  = (const float*)d_in[0];
  const float* Wq = (const float*)d_in[2];
  const float* bq = (const float*)d_in[3];
  const float* Wk = (const float*)d_in[4];
  const float* bk = (const float*)d_in[5];
  const float* Wv = (const float*)d_in[6];
  const float* bv = (const float*)d_in[7];
  const float* Wo = (const float*)d_in[8];
  const float* bo = (const float*)d_in[9];
  const float* rb = (const float*)d_in[10];

  char* ws = (char*)d_ws;
  u16* xb  = (u16*)(ws);
  u16* wqb = (u16*)(ws + (8l  << 20));
  u16* wkb = (u16*)(ws + (10l << 20));
  u16* wvb = (u16*)(ws + (12l << 20));
  u16* wob = (u16*)(ws + (14l << 20));
  u16* Qb  = (u16*)(ws + (16l << 20));
  u16* Kb  = (u16*)d_out;
  u16* Vtg = (u16*)((char*)d_out + (8l << 20));

  cast_all_kernel<<<8192, 256, 0, stream>>>(x, Wq, Wk, Wv, Wo, xb, wqb, wkb, wvb, wob);
  gemm_qkv<<<192, 512, 0, stream>>>(xb, wqb, wkb, wvb, bq, bk, bv, Qb, Kb, Vtg);
  attn_strip<<<512, 512, 0, stream>>>(Qb, Kb, Vtg, rb, Qb);
  gemm_out<<<dim3(32, 8), 256, 0, stream>>>(Qb, wob, bo, (float*)d_out);
}